// Round 1
// baseline (104.827 us; speedup 1.0000x reference)
//
#include <hip/hip_runtime.h>
#include <hip/hip_bf16.h>
#include <stdint.h>

// Problem constants (reference: VOCAB=30000, EMB=128, ENC=128, BS=256, DEPTH=10)
#define VOCAB 30000
#define EMB 128
#define ENC 128
#define BS 256
#define NNODES 1023   // 2^10 - 1

typedef short short8 __attribute__((ext_vector_type(8)));
typedef float f32x4 __attribute__((ext_vector_type(4)));

__device__ __forceinline__ unsigned short f2bf(float x) {
    // round-to-nearest-even fp32 -> bf16
    uint32_t u = __float_as_uint(x);
    uint32_t r = u + 0x7fffu + ((u >> 16) & 1u);
    return (unsigned short)(r >> 16);
}

// ---- Kernel 0: convert W_c (128x128 fp32) to bf16 ----
__global__ void convw_k(const float* __restrict__ W, unsigned short* __restrict__ Wbf) {
    int i = blockIdx.x * 256 + threadIdx.x;
    if (i < ENC * EMB) Wbf[i] = f2bf(W[i]);
}

// ---- Kernel 1: P[v][o] = dot(emb[v,:], W[o,:]) + b[o], via bf16 MFMA ----
// Per block: 4 waves x 16 v-rows = 64 rows. No LDS; W bf16 is L1-hot (32KB).
// A-frag layout (16x16x32): lane holds A[m=lane&15][k=(lane>>4)*8 + j], j=0..7
// B-frag layout:            lane holds B[k=(lane>>4)*8+j][n=lane&15] = W[n][k]
// C/D layout: col = lane&15 (o), row = (lane>>4)*4 + reg (v)
__global__ void __launch_bounds__(256) project_k(const float* __restrict__ emb,
                                                 const unsigned short* __restrict__ Wbf,
                                                 const float* __restrict__ bias,
                                                 float* __restrict__ P) {
    const int wave = threadIdx.x >> 6;
    const int lane = threadIdx.x & 63;
    const int r = lane & 15;
    const int q = lane >> 4;
    const int v0 = blockIdx.x * 64 + wave * 16;

    int vr = v0 + r;
    if (vr > VOCAB - 1) vr = VOCAB - 1;   // clamp reads in tail block

    // Load + convert A fragments for all K=128 (4 chunks of 32)
    short8 af[4];
    const float* erow = emb + (size_t)vr * EMB + q * 8;
#pragma unroll
    for (int kk = 0; kk < 4; kk++) {
        const float4 x0 = *(const float4*)(erow + kk * 32);
        const float4 x1 = *(const float4*)(erow + kk * 32 + 4);
        short8 a;
        a[0] = (short)f2bf(x0.x); a[1] = (short)f2bf(x0.y);
        a[2] = (short)f2bf(x0.z); a[3] = (short)f2bf(x0.w);
        a[4] = (short)f2bf(x1.x); a[5] = (short)f2bf(x1.y);
        a[6] = (short)f2bf(x1.z); a[7] = (short)f2bf(x1.w);
        af[kk] = a;
    }

#pragma unroll
    for (int ot = 0; ot < 8; ot++) {
        const int o0 = ot * 16;
        f32x4 acc = {0.f, 0.f, 0.f, 0.f};
        const unsigned short* wrow = Wbf + (o0 + r) * EMB + q * 8;
#pragma unroll
        for (int kk = 0; kk < 4; kk++) {
            short8 bf = *(const short8*)(wrow + kk * 32);
            acc = __builtin_amdgcn_mfma_f32_16x16x32_bf16(af[kk], bf, acc, 0, 0, 0);
        }
        const float bb = bias[o0 + r];   // col = lane&15 = r
#pragma unroll
        for (int i = 0; i < 4; i++) {
            const int vo = v0 + q * 4 + i;
            if (vo < VOCAB) P[(size_t)vo * ENC + o0 + r] = acc[i] + bb;
        }
    }
}

// ---- Kernel 2: bottom 5 tree levels. 32 subtrees (roots 31..62) x 256 batches.
// Heap: descendants of root rg at relative depth k are contiguous: ((rg+1)<<k)-1, count 2^k.
__global__ void subtree_k(const int* __restrict__ tokens, const float* __restrict__ P,
                          float* __restrict__ sums, float* __restrict__ maxes) {
    const int st = blockIdx.x;   // 0..31
    const int b  = blockIdx.y;   // 0..255
    const int ch = threadIdx.x;  // 0..127
    const int* tb = tokens + b * NNODES;
    const int rp1 = 32 + st;     // root+1, root = 31+st

    float m = -3.0e38f;
    float v[16];
    int base = (rp1 << 4) - 1;   // 16 leaves (global level 9)
#pragma unroll
    for (int i = 0; i < 16; i++) v[i] = P[tb[base + i] * ENC + ch];
#pragma unroll
    for (int i = 0; i < 16; i++) m = fmaxf(m, v[i]);

    float u[8];
    base = (rp1 << 3) - 1;
#pragma unroll
    for (int i = 0; i < 8; i++) {
        u[i] = P[tb[base + i] * ENC + ch] + v[2 * i] + v[2 * i + 1];
        m = fmaxf(m, u[i]);
    }
    float w4[4];
    base = (rp1 << 2) - 1;
#pragma unroll
    for (int i = 0; i < 4; i++) {
        w4[i] = P[tb[base + i] * ENC + ch] + u[2 * i] + u[2 * i + 1];
        m = fmaxf(m, w4[i]);
    }
    float w2[2];
    base = (rp1 << 1) - 1;
#pragma unroll
    for (int i = 0; i < 2; i++) {
        w2[i] = P[tb[base + i] * ENC + ch] + w4[2 * i] + w4[2 * i + 1];
        m = fmaxf(m, w2[i]);
    }
    const float s = P[tb[rp1 - 1] * ENC + ch] + w2[0] + w2[1];
    m = fmaxf(m, s);

    const int idx = (b * 32 + st) * ENC + ch;
    sums[idx] = s;
    maxes[idx] = m;
}

// ---- Kernel 3: top 5 levels (nodes 0..30); children of node 15+i are subtree roots 31+2i, 32+2i.
__global__ void topfold_k(const int* __restrict__ tokens, const float* __restrict__ P,
                          const float* __restrict__ sums, const float* __restrict__ maxes,
                          float* __restrict__ out) {
    const int b = blockIdx.x;
    const int ch = threadIdx.x;
    const int* tb = tokens + b * NNODES;

    float m = -3.0e38f;
    float v[32];
#pragma unroll
    for (int i = 0; i < 32; i++) v[i] = sums[(b * 32 + i) * ENC + ch];
#pragma unroll
    for (int i = 0; i < 32; i++) m = fmaxf(m, maxes[(b * 32 + i) * ENC + ch]);

    float u[16];  // nodes 15..30
#pragma unroll
    for (int i = 0; i < 16; i++) {
        u[i] = P[tb[15 + i] * ENC + ch] + v[2 * i] + v[2 * i + 1];
        m = fmaxf(m, u[i]);
    }
    float w8[8];  // nodes 7..14
#pragma unroll
    for (int i = 0; i < 8; i++) {
        w8[i] = P[tb[7 + i] * ENC + ch] + u[2 * i] + u[2 * i + 1];
        m = fmaxf(m, w8[i]);
    }
    float w4[4];  // nodes 3..6
#pragma unroll
    for (int i = 0; i < 4; i++) {
        w4[i] = P[tb[3 + i] * ENC + ch] + w8[2 * i] + w8[2 * i + 1];
        m = fmaxf(m, w4[i]);
    }
    float w2[2];  // nodes 1,2
#pragma unroll
    for (int i = 0; i < 2; i++) {
        w2[i] = P[tb[1 + i] * ENC + ch] + w4[2 * i] + w4[2 * i + 1];
        m = fmaxf(m, w2[i]);
    }
    const float s0 = P[tb[0] * ENC + ch] + w2[0] + w2[1];
    m = fmaxf(m, s0);

    out[b * ENC + ch] = m;
}

extern "C" void kernel_launch(void* const* d_in, const int* in_sizes, int n_in,
                              void* d_out, int out_size, void* d_ws, size_t ws_size,
                              hipStream_t stream) {
    const int*   tokens = (const int*)d_in[0];    // (256,1023) int32
    const float* emb    = (const float*)d_in[1];  // (30000,128) f32
    const float* W_c    = (const float*)d_in[2];  // (128,128) f32
    const float* b_c    = (const float*)d_in[3];  // (128,) f32
    float* out = (float*)d_out;                   // (256,128) f32

    // Workspace layout (needs ~23.8 MB):
    //   P    : 30000*128 f32 = 15,360,000 B
    //   Wbf  : 128*128 bf16  =     32,768 B
    //   sums : 256*32*128 f32 =  4,194,304 B
    //   maxes: 256*32*128 f32 =  4,194,304 B
    char* ws = (char*)d_ws;
    float*          P     = (float*)ws;
    unsigned short* Wbf   = (unsigned short*)(ws + 15360000);
    float*          sums  = (float*)(ws + 15360000 + 32768);
    float*          maxes = sums + BS * 32 * ENC;

    convw_k<<<64, 256, 0, stream>>>(W_c, Wbf);
    project_k<<<(VOCAB + 63) / 64, 256, 0, stream>>>(emb, Wbf, b_c, P);
    subtree_k<<<dim3(32, BS), 128, 0, stream>>>(tokens, P, sums, maxes);
    topfold_k<<<BS, 128, 0, stream>>>(tokens, P, sums, maxes, out);
}

// Round 2
// 96.010 us; speedup vs baseline: 1.0918x; 1.0918x over previous
//
#include <hip/hip_runtime.h>
#include <hip/hip_bf16.h>
#include <stdint.h>

// Problem constants (reference: VOCAB=30000, EMB=128, ENC=128, BS=256, DEPTH=10)
#define VOCAB 30000
#define EMB 128
#define ENC 128
#define BS 256
#define NNODES 1023   // 2^10 - 1

typedef short short8 __attribute__((ext_vector_type(8)));
typedef float f32x4 __attribute__((ext_vector_type(4)));

__device__ __forceinline__ unsigned short f2bf(float x) {
    // round-to-nearest-even fp32 -> bf16
    uint32_t u = __float_as_uint(x);
    uint32_t r = u + 0x7fffu + ((u >> 16) & 1u);
    return (unsigned short)(r >> 16);
}
__device__ __forceinline__ float bf2f(unsigned short h) {
    return __uint_as_float(((uint32_t)h) << 16);
}

// ---- Kernel 1: P[v][o] = bf16( dot(emb[v,:], W[o,:]) + b[o] ), via bf16 MFMA ----
// W converted fp32->bf16 into LDS once per block (row stride padded to 136 shorts
// => ds_read_b128 lands on 2-way bank aliasing, which is free on gfx950).
// A-frag layout (16x16x32): lane holds A[m=lane&15][k=(lane>>4)*8 + j], j=0..7
// B-frag layout:            lane holds B[k=(lane>>4)*8+j][n=lane&15] = W[n][k]
// C/D layout: col = lane&15 (o), row = (lane>>4)*4 + reg (v)   [m89-verified]
#define WLD 136
__global__ void __launch_bounds__(256) project_k(const float* __restrict__ emb,
                                                 const float* __restrict__ W,
                                                 const float* __restrict__ bias,
                                                 unsigned short* __restrict__ P) {
    __shared__ unsigned short Wlds[ENC * WLD];   // 34,816 B

    // Stage W as bf16 into LDS (coalesced fp32 reads, 64 elems/thread)
    for (int i = threadIdx.x; i < ENC * EMB; i += 256) {
        const int o = i >> 7, k = i & 127;
        Wlds[o * WLD + k] = f2bf(W[i]);
    }
    __syncthreads();

    const int wave = threadIdx.x >> 6;
    const int lane = threadIdx.x & 63;
    const int r = lane & 15;
    const int q = lane >> 4;
    const int v0 = blockIdx.x * 64 + wave * 16;

    int vr = v0 + r;
    if (vr > VOCAB - 1) vr = VOCAB - 1;   // clamp reads in tail block

    // Load + convert A fragments for all K=128 (4 chunks of 32)
    short8 af[4];
    const float* erow = emb + (size_t)vr * EMB + q * 8;
#pragma unroll
    for (int kk = 0; kk < 4; kk++) {
        const float4 x0 = *(const float4*)(erow + kk * 32);
        const float4 x1 = *(const float4*)(erow + kk * 32 + 4);
        short8 a;
        a[0] = (short)f2bf(x0.x); a[1] = (short)f2bf(x0.y);
        a[2] = (short)f2bf(x0.z); a[3] = (short)f2bf(x0.w);
        a[4] = (short)f2bf(x1.x); a[5] = (short)f2bf(x1.y);
        a[6] = (short)f2bf(x1.z); a[7] = (short)f2bf(x1.w);
        af[kk] = a;
    }

#pragma unroll
    for (int ot = 0; ot < 8; ot++) {
        const int o0 = ot * 16;
        f32x4 acc = {0.f, 0.f, 0.f, 0.f};
        const unsigned short* wrow = Wlds + (o0 + r) * WLD + q * 8;
#pragma unroll
        for (int kk = 0; kk < 4; kk++) {
            short8 bf = *(const short8*)(wrow + kk * 32);
            acc = __builtin_amdgcn_mfma_f32_16x16x32_bf16(af[kk], bf, acc, 0, 0, 0);
        }
        const float bb = bias[o0 + r];   // col = lane&15 = r
#pragma unroll
        for (int i = 0; i < 4; i++) {
            const int vo = v0 + q * 4 + i;
            if (vo < VOCAB) P[(size_t)vo * ENC + o0 + r] = f2bf(acc[i] + bb);
        }
    }
}

// ---- Kernel 2: bottom 5 tree levels. 32 subtrees (roots 31..62) x 256 batches.
// Heap: descendants of root rg at relative depth k are contiguous: ((rg+1)<<k)-1, count 2^k.
__global__ void subtree_k(const int* __restrict__ tokens, const unsigned short* __restrict__ P,
                          float* __restrict__ sums, float* __restrict__ maxes) {
    const int st = blockIdx.x;   // 0..31
    const int b  = blockIdx.y;   // 0..255
    const int ch = threadIdx.x;  // 0..127
    const int* tb = tokens + b * NNODES;
    const int rp1 = 32 + st;     // root+1, root = 31+st

    float m = -3.0e38f;
    float v[16];
    int base = (rp1 << 4) - 1;   // 16 leaves (global level 9)
#pragma unroll
    for (int i = 0; i < 16; i++) v[i] = bf2f(P[tb[base + i] * ENC + ch]);
#pragma unroll
    for (int i = 0; i < 16; i++) m = fmaxf(m, v[i]);

    float u[8];
    base = (rp1 << 3) - 1;
#pragma unroll
    for (int i = 0; i < 8; i++) {
        u[i] = bf2f(P[tb[base + i] * ENC + ch]) + v[2 * i] + v[2 * i + 1];
        m = fmaxf(m, u[i]);
    }
    float w4[4];
    base = (rp1 << 2) - 1;
#pragma unroll
    for (int i = 0; i < 4; i++) {
        w4[i] = bf2f(P[tb[base + i] * ENC + ch]) + u[2 * i] + u[2 * i + 1];
        m = fmaxf(m, w4[i]);
    }
    float w2[2];
    base = (rp1 << 1) - 1;
#pragma unroll
    for (int i = 0; i < 2; i++) {
        w2[i] = bf2f(P[tb[base + i] * ENC + ch]) + w4[2 * i] + w4[2 * i + 1];
        m = fmaxf(m, w2[i]);
    }
    const float s = bf2f(P[tb[rp1 - 1] * ENC + ch]) + w2[0] + w2[1];
    m = fmaxf(m, s);

    const int idx = (b * 32 + st) * ENC + ch;
    sums[idx] = s;
    maxes[idx] = m;
}

// ---- Kernel 3: top 5 levels (nodes 0..30); children of node 15+i are subtree roots 31+2i, 32+2i.
__global__ void topfold_k(const int* __restrict__ tokens, const unsigned short* __restrict__ P,
                          const float* __restrict__ sums, const float* __restrict__ maxes,
                          float* __restrict__ out) {
    const int b = blockIdx.x;
    const int ch = threadIdx.x;
    const int* tb = tokens + b * NNODES;

    float m = -3.0e38f;
    float v[32];
#pragma unroll
    for (int i = 0; i < 32; i++) v[i] = sums[(b * 32 + i) * ENC + ch];
#pragma unroll
    for (int i = 0; i < 32; i++) m = fmaxf(m, maxes[(b * 32 + i) * ENC + ch]);

    float u[16];  // nodes 15..30
#pragma unroll
    for (int i = 0; i < 16; i++) {
        u[i] = bf2f(P[tb[15 + i] * ENC + ch]) + v[2 * i] + v[2 * i + 1];
        m = fmaxf(m, u[i]);
    }
    float w8[8];  // nodes 7..14
#pragma unroll
    for (int i = 0; i < 8; i++) {
        w8[i] = bf2f(P[tb[7 + i] * ENC + ch]) + u[2 * i] + u[2 * i + 1];
        m = fmaxf(m, w8[i]);
    }
    float w4[4];  // nodes 3..6
#pragma unroll
    for (int i = 0; i < 4; i++) {
        w4[i] = bf2f(P[tb[3 + i] * ENC + ch]) + w8[2 * i] + w8[2 * i + 1];
        m = fmaxf(m, w4[i]);
    }
    float w2[2];  // nodes 1,2
#pragma unroll
    for (int i = 0; i < 2; i++) {
        w2[i] = bf2f(P[tb[1 + i] * ENC + ch]) + w4[2 * i] + w4[2 * i + 1];
        m = fmaxf(m, w2[i]);
    }
    const float s0 = bf2f(P[tb[0] * ENC + ch]) + w2[0] + w2[1];
    m = fmaxf(m, s0);

    out[b * ENC + ch] = m;
}

extern "C" void kernel_launch(void* const* d_in, const int* in_sizes, int n_in,
                              void* d_out, int out_size, void* d_ws, size_t ws_size,
                              hipStream_t stream) {
    const int*   tokens = (const int*)d_in[0];    // (256,1023) int32
    const float* emb    = (const float*)d_in[1];  // (30000,128) f32
    const float* W_c    = (const float*)d_in[2];  // (128,128) f32
    const float* b_c    = (const float*)d_in[3];  // (128,) f32
    float* out = (float*)d_out;                   // (256,128) f32

    // Workspace layout (~16.1 MB):
    //   P    : 30000*128 bf16 =  7,680,000 B
    //   sums : 256*32*128 f32 =  4,194,304 B
    //   maxes: 256*32*128 f32 =  4,194,304 B
    char* ws = (char*)d_ws;
    unsigned short* P     = (unsigned short*)ws;
    float*          sums  = (float*)(ws + 7680000);
    float*          maxes = sums + BS * 32 * ENC;

    project_k<<<(VOCAB + 63) / 64, 256, 0, stream>>>(emb, W_c, b_c, P);
    subtree_k<<<dim3(32, BS), 128, 0, stream>>>(tokens, P, sums, maxes);
    topfold_k<<<BS, 128, 0, stream>>>(tokens, P, sums, maxes, out);
}